// Round 3
// baseline (526.447 us; speedup 1.0000x reference)
//
#include <hip/hip_runtime.h>
#include <stdint.h>

typedef __attribute__((ext_vector_type(8))) short short8;
typedef __attribute__((ext_vector_type(4))) float floatx4;
typedef unsigned short ushort_t;

__device__ __forceinline__ ushort_t f2bf(float f) {
    union { float f; unsigned int i; } v; v.f = f;
    unsigned int r = v.i + 0x7fffu + ((v.i >> 16) & 1u);  // RNE
    return (ushort_t)(r >> 16);
}

// B=8, N=1024 (rows R=8192), P=16, D=512 (GEMM K), E=8192 (P*D)
// All global I/O fp32; GEMM operands converted to bf16 for MFMA.

// ---------- W2 fp32 [512][8192] -> W2T bf16 [8192][512] ----------
__global__ __launch_bounds__(256) void k_prep(
    const float* __restrict__ W2, ushort_t* __restrict__ W2T)
{
    __shared__ float t[32][33];
    const int tid = threadIdx.x;
    const int tx = tid & 31, ty = tid >> 5;      // 32 x 8
    const int e0 = blockIdx.x * 32, k0 = blockIdx.y * 32;
#pragma unroll
    for (int i = 0; i < 4; ++i)
        t[ty + i * 8][tx] = W2[(size_t)(k0 + ty + i * 8) * 8192 + e0 + tx];
    __syncthreads();
#pragma unroll
    for (int i = 0; i < 4; ++i)
        W2T[(size_t)(e0 + ty + i * 8) * 512 + k0 + tx] = f2bf(t[tx][ty + i * 8]);
}

// ---------- h[r][d] = relu(xp[r][:16] @ W1[:, d] + b1[d]), bf16 out ----------
__global__ __launch_bounds__(256) void k1_hidden(
    const float* __restrict__ x, const float* __restrict__ W1,
    const float* __restrict__ b1, ushort_t* __restrict__ h)
{
    __shared__ float xs[16];
    const int r = blockIdx.x;
    const int tid = threadIdx.x;
    if (tid < 16) xs[tid] = x[r * 16 + tid];
    __syncthreads();
#pragma unroll
    for (int dd = 0; dd < 2; ++dd) {
        int d = tid + dd * 256;
        float s = b1[d];
#pragma unroll
        for (int p = 0; p < 16; ++p)
            s += xs[p] * W1[p * 512 + d];
        s = s > 0.f ? s : 0.f;
        h[(size_t)r * 512 + d] = f2bf(s);
    }
}

// ---------- main GEMM: exp(relu(h @ W2 + b2)) -> d_out (fp32) + column sums ----------
// 128x128 block tile, 4 waves, each wave 4x4 tiles of mfma_f32_16x16x32_bf16
#define BK 32
__global__ __launch_bounds__(256) void k2_gemm(
    const ushort_t* __restrict__ h,     // [8192][512] bf16
    const ushort_t* __restrict__ W2T,   // [8192][512] bf16
    const float* __restrict__ b2,       // [8192] fp32
    float* __restrict__ expws,          // [8192][8192] fp32 == d_out as scratch
    float* __restrict__ denom)          // [8][8192]
{
    __shared__ __align__(16) ushort_t As[128 * BK];
    __shared__ __align__(16) ushort_t Bs[128 * BK];
    const int tid = threadIdx.x;
    const int lane = tid & 63;
    const int wave = tid >> 6;
    const int quad = lane >> 4;
    const int l16 = lane & 15;
    const int i0 = blockIdx.x * 128;   // M base
    const int e0 = blockIdx.y * 128;   // E base
    const int wr = (wave >> 1) * 64;
    const int wc = (wave & 1) * 64;

    floatx4 acc[4][4];
#pragma unroll
    for (int i = 0; i < 4; ++i)
#pragma unroll
        for (int j = 0; j < 4; ++j)
            acc[i][j] = (floatx4){0.f, 0.f, 0.f, 0.f};

    for (int k0 = 0; k0 < 512; k0 += BK) {
#pragma unroll
        for (int s = 0; s < 2; ++s) {
            int q = tid + s * 256;         // chunk id 0..511 (16B chunks)
            int row = q >> 2;              // 0..127 local row
            int c = q & 3;                 // chunk within row
            uint4 va = *reinterpret_cast<const uint4*>(&h[(size_t)(i0 + row) * 512 + k0 + c * 8]);
            uint4 vb = *reinterpret_cast<const uint4*>(&W2T[(size_t)(e0 + row) * 512 + k0 + c * 8]);
            *reinterpret_cast<uint4*>(&As[row * 32 + ((c ^ (row & 3)) << 3)]) = va;
            *reinterpret_cast<uint4*>(&Bs[row * 32 + ((c ^ (row & 3)) << 3)]) = vb;
        }
        __syncthreads();
        short8 af[4], bf[4];
#pragma unroll
        for (int i = 0; i < 4; ++i) {
            int m = wr + i * 16 + l16;
            af[i] = *reinterpret_cast<const short8*>(&As[m * 32 + ((quad ^ (m & 3)) << 3)]);
            int n = wc + i * 16 + l16;
            bf[i] = *reinterpret_cast<const short8*>(&Bs[n * 32 + ((quad ^ (n & 3)) << 3)]);
        }
#pragma unroll
        for (int i = 0; i < 4; ++i)
#pragma unroll
            for (int j = 0; j < 4; ++j)
                acc[i][j] = __builtin_amdgcn_mfma_f32_16x16x32_bf16(af[i], bf[j], acc[i][j], 0, 0, 0);
        __syncthreads();
    }

    // epilogue: bias, relu, exp, store fp32, column sums -> atomicAdd
    const int b_batch = i0 >> 10;
#pragma unroll
    for (int j = 0; j < 4; ++j) {
        int eg = e0 + wc + j * 16 + l16;
        float b2v = b2[eg];
        float csj = 0.f;
#pragma unroll
        for (int i = 0; i < 4; ++i) {
            int rbase = i0 + wr + i * 16 + quad * 4;
#pragma unroll
            for (int r = 0; r < 4; ++r) {
                float v = acc[i][j][r] + b2v;
                v = v > 0.f ? v : 0.f;
                float ev = __expf(v);
                expws[(size_t)(rbase + r) * 8192 + eg] = ev;
                csj += ev;
            }
        }
        csj += __shfl_xor(csj, 16, 64);
        csj += __shfl_xor(csj, 32, 64);
        if (lane < 16) atomicAdd(&denom[b_batch * 8192 + eg], csj);
    }
}

// ---------- reciprocal denominators ----------
__global__ __launch_bounds__(256) void k_rdenom(const float* __restrict__ denom,
                                                float* __restrict__ rden)
{
    int i = blockIdx.x * 256 + threadIdx.x;
    rden[i] = 1.0f / denom[i];
}

// ---------- finalize IN-PLACE on d_out (fp32): normalize, *xp, avgpool over d ----------
__global__ __launch_bounds__(256) void k3_finalize(
    const float* __restrict__ x,         // xp [8192][16]
    const float* __restrict__ rdenom,    // [8][8192]
    float* __restrict__ out)             // [8192][8192] in = exp, out = final
{
    __shared__ float xs[16];
    __shared__ float g[16 * 514];        // [p][d], stride 514 to spread banks
    const int row = blockIdx.x;          // b*1024 + n
    const int b = row >> 10;
    const int tid = threadIdx.x;
    if (tid < 16) xs[tid] = x[row * 16 + tid];
    __syncthreads();
    const float* erow = out + (size_t)row * 8192;
    const float* rd = rdenom + (size_t)b * 8192;
#pragma unroll
    for (int i = 0; i < 8; ++i) {
        int e4 = (tid + i * 256) * 4;    // 4 consecutive e: same d, p = p0..p0+3
        float4 ev = *reinterpret_cast<const float4*>(erow + e4);
        float4 r4 = *reinterpret_cast<const float4*>(rd + e4);
        int d = e4 >> 4;
        int p0 = e4 & 15;
        g[(p0 + 0) * 514 + d] = ev.x * r4.x * xs[p0 + 0];
        g[(p0 + 1) * 514 + d] = ev.y * r4.y * xs[p0 + 1];
        g[(p0 + 2) * 514 + d] = ev.z * r4.z * xs[p0 + 2];
        g[(p0 + 3) * 514 + d] = ev.w * r4.w * xs[p0 + 3];
    }
    __syncthreads();
    float* orow = out + (size_t)row * 8192;
    const float inv3 = 1.f / 3.f;
#pragma unroll
    for (int i = 0; i < 8; ++i) {
        int flat = tid * 4 + i * 1024;
        int p = flat >> 9;
        int d = flat & 511;              // multiple of 4
        const float* gr = g + p * 514;
        float gm1 = (d > 0) ? gr[d - 1] : 0.f;
        float g0 = gr[d], g1 = gr[d + 1], g2 = gr[d + 2], g3 = gr[d + 3];
        float g4 = (d < 508) ? gr[d + 4] : 0.f;
        float4 o;
        o.x = (gm1 + g0 + g1) * inv3;
        o.y = (g0 + g1 + g2) * inv3;
        o.z = (g1 + g2 + g3) * inv3;
        o.w = (g2 + g3 + g4) * inv3;
        *reinterpret_cast<float4*>(orow + p * 512 + d) = o;
    }
}

extern "C" void kernel_launch(void* const* d_in, const int* in_sizes, int n_in,
                              void* d_out, int out_size, void* d_ws, size_t ws_size,
                              hipStream_t stream)
{
    const float* x  = (const float*)d_in[0];   // 8*32*512
    const float* W1 = (const float*)d_in[1];   // 16*512
    const float* b1 = (const float*)d_in[2];   // 512
    const float* W2 = (const float*)d_in[3];   // 512*8192
    const float* b2 = (const float*)d_in[4];   // 8192
    float* out = (float*)d_out;                // 8192*16*512 fp32

    char* ws = (char*)d_ws;
    ushort_t* h     = (ushort_t*)(ws);                              // 8 MiB
    ushort_t* W2T   = (ushort_t*)(ws + (size_t)(8u << 20));         // 8 MiB
    float*    denom = (float*)(ws + (size_t)(16u << 20));           // 256 KiB
    float*    rden  = (float*)(ws + (size_t)(16u << 20) + (256u << 10));

    hipMemsetAsync(denom, 0, 65536 * sizeof(float), stream);
    k_prep<<<dim3(256, 16), 256, 0, stream>>>(W2, W2T);
    k1_hidden<<<8192, 256, 0, stream>>>(x, W1, b1, h);
    k2_gemm<<<dim3(64, 64), 256, 0, stream>>>(h, W2T, b2, out, denom);
    k_rdenom<<<256, 256, 0, stream>>>(denom, rden);
    k3_finalize<<<8192, 256, 0, stream>>>(x, rden, out);
}